// Round 8
// baseline (786.263 us; speedup 1.0000x reference)
//
#include <hip/hip_runtime.h>

typedef __attribute__((ext_vector_type(8))) short short8;
typedef __attribute__((ext_vector_type(4))) float f32x4;

constexpr int Bn  = 4;
constexpr int Tn  = 2048;
constexpr int Sn  = 2048;
constexpr int Dn  = 512;
constexpr int Hn  = 8;
constexpr int DKn = 64;
constexpr int DVn = 64;
constexpr int HDn = 512;   // H*DK = H*DV
constexpr int SKn = 30;    // sample_k
constexpr int Un  = 30;    // top-u
constexpr int NGroups = Un;                 // Gu=1: one u per attention block
constexpr int NAttnG  = Bn * Hn * NGroups;  // 960 attention blocks
constexpr int NOutF   = (Bn * Tn) / 8;      // 1024 out-base blocks (8 rows each)
constexpr int NGemm  = 768;                 // 3 z x 128 m-blocks x 2 n-blocks
constexpr float kScale = 0.125f;            // 1/sqrt(DK)

constexpr int NWsplit = 192;    // W transpose+split blocks
constexpr int NVPart  = 64;     // v-mean partial blocks (prefix of sampled launch)
constexpr int NSampled = Bn * Tn;           // 8192

// fscores fill distribution across the three launches' spare write BW.
constexpr int NFillG = 10240;   // gemm launch: rows [0, 40960)
constexpr int NFillS = 2048;    // sampled launch: rows [40960, 49152)
constexpr int NFillT = 4096;    // topk launch: rows [49152, 65536) == Wt scratch (after gemm)
constexpr int FillRowsG = 0;
constexpr int FillRowsS = NFillG * 4;             // 40960
constexpr int FillRowsT = (NFillG + NFillS) * 4;  // 49152

__device__ __forceinline__ ushort bf16_rne(float x) {
  unsigned u = __float_as_uint(x);
  return (ushort)((u + 0x7fffu + ((u >> 16) & 1u)) >> 16);
}
__device__ __forceinline__ float bf16f(ushort h) {
  return __uint_as_float(((unsigned)h) << 16);
}
__device__ __forceinline__ void nt_store4(f32x4* p, f32x4 v) {
  __builtin_nontemporal_store(v, p);
}
__device__ __forceinline__ void fill_rows4_256(float* fscores, size_t r0, int tid) {
  const float c = 1.0f / Sn;
  const f32x4 c4v = {c, c, c, c};
  f32x4* fs4 = (f32x4*)fscores + r0 * (Sn / 4);
#pragma unroll
  for (int i = 0; i < 8; ++i) nt_store4(fs4 + i * 256 + tid, c4v);
}
// async global->LDS DMA, 16B per lane; LDS dest = base + lane*16 (wave-uniform base)
__device__ __forceinline__ void gload_lds16(const void* g, void* lds) {
  __builtin_amdgcn_global_load_lds((const __attribute__((address_space(1))) void*)g,
                                   (__attribute__((address_space(3))) void*)lds, 16, 0, 0);
}

#define MFMA(accv, av, bv) \
  asm volatile("v_mfma_f32_16x16x32_bf16 %0, %1, %2, %0" : "+v"(accv) : "v"(av), "v"(bv))

// ------------- prep: transpose+split W into bf16 hi/lo (W is tiny: 3 MB, stays L2/L3 resident) -------------
__global__ __launch_bounds__(256) void prep_split_kernel(
    const float* __restrict__ Wq, const float* __restrict__ Wk, const float* __restrict__ Wv,
    ushort* __restrict__ WtH, ushort* __restrict__ WtL) {
  const int tid = threadIdx.x;
  const int bid = blockIdx.x;

  // W[k][n] -> Wt[n][k], split into bf16 hi/lo
  const int z = bid / 64, t = bid % 64;
  const int k0 = (t >> 3) * 64, n0 = (t & 7) * 64;
  const float* W = (z == 0) ? Wq : (z == 1) ? Wk : Wv;
  __shared__ float tile[64][65];
  const int r = tid >> 2, c0 = (tid & 3) * 16;
#pragma unroll
  for (int i = 0; i < 16; i += 4) {
    const float4 vv = *(const float4*)(W + (size_t)(k0 + r) * HDn + n0 + c0 + i);
    tile[r][c0 + i] = vv.x; tile[r][c0 + i + 1] = vv.y;
    tile[r][c0 + i + 2] = vv.z; tile[r][c0 + i + 3] = vv.w;
  }
  __syncthreads();
  unsigned hp[8], lp[8];
#pragma unroll
  for (int i = 0; i < 16; i += 2) {
    const float x0 = tile[c0 + i][r];
    const float x1 = tile[c0 + i + 1][r];
    const ushort h0 = bf16_rne(x0), h1 = bf16_rne(x1);
    const ushort l0 = bf16_rne(x0 - bf16f(h0)), l1 = bf16_rne(x1 - bf16f(h1));
    hp[i >> 1] = (unsigned)h0 | ((unsigned)h1 << 16);
    lp[i >> 1] = (unsigned)l0 | ((unsigned)l1 << 16);
  }
  const size_t off = (size_t)(z * 512 + n0 + r) * 512 + k0 + c0;
  *(uint4*)(WtH + off)     = make_uint4(hp[0], hp[1], hp[2], hp[3]);
  *(uint4*)(WtH + off + 8) = make_uint4(hp[4], hp[5], hp[6], hp[7]);
  *(uint4*)(WtL + off)     = make_uint4(lp[0], lp[1], lp[2], lp[3]);
  *(uint4*)(WtL + off + 8) = make_uint4(lp[4], lp[5], lp[6], lp[7]);
}

// ------------- mega A: blocks[0..767] MFMA bf16x3 q/k/v GEMM (A split in-kernel; B via
//               global_load_lds DMA with source-side swizzle); rest fill fscores [0,40960) -------------
__global__ __launch_bounds__(256, 2) void gemm_fill_kernel(
    const float* __restrict__ xq, const float* __restrict__ xk, const float* __restrict__ xv,
    const ushort* __restrict__ WtH, const ushort* __restrict__ WtL,
    const float* __restrict__ bq, const float* __restrict__ bk, const float* __restrict__ bv,
    float* __restrict__ qo, float* __restrict__ ko, float* __restrict__ vo,
    float* __restrict__ fscores) {
  const int bid = blockIdx.x;
  const int tid = threadIdx.x;

  if (bid >= NGemm) {
    fill_rows4_256(fscores, (size_t)FillRowsG + (size_t)(bid - NGemm) * 4, tid);
    return;
  }

  // LDS: granule-XOR swizzled (granule = 8 ushorts = 16B): slot s of row n holds source
  // granule s ^ ((n>>1)&3). A: via swizzled ds_write. B: via DMA with swizzled SOURCE addr.
  __shared__ ushort AsH[64][32];    // 4 KB
  __shared__ ushort AsL[64][32];
  __shared__ ushort BsH[256][32];   // 16 KB
  __shared__ ushort BsL[256][32];   // total 40 KB

  const int z = bid >> 8;            // 0..2 selects q/k/v
  const int rem = bid & 255;
  const int bm = (rem >> 1) * 64;    // 64-row A block
  const int bn = (rem & 1) * 256;    // 256-col B block
  const float* X = (z == 0) ? xq : (z == 1) ? xk : xv;
  const float* bias = (z == 0) ? bq : (z == 1) ? bk : bv;
  float* Y = (z == 0) ? qo : (z == 1) ? ko : vo;

  const int lane = tid & 63;
  const int wave = tid >> 6;                 // wave tile: 64m x 64n
  const int fr = lane & 15;                  // fragment row/col
  const int gk = lane >> 4;                  // k-granule 0..3 within 32

  // A staging: thread loads row ar, k-granule ag (8 fp32 = 32B)
  const int ar = tid >> 2, ag = tid & 3;
  const float* xrow = X + (size_t)(bm + ar) * Dn + ag * 8;
  const int agq = (ag ^ ((ar >> 1) & 3)) * 8;

  // B staging via DMA: wave w covers rows [w*64, w*64+64) of BsH/BsL in 4 chunks of 16 rows.
  // lane l -> row chunkBase + (l>>2), LDS slot (l&3); source granule = (l&3)^((l>>3)&3)
  // (== slot ^ ((row>>1)&3) since chunkBase is a multiple of 16).
  const int gsrc = (lane & 3) ^ ((lane >> 3) & 3);
  const ushort* bgH = WtH + (size_t)(z * 512 + bn + wave * 64 + (lane >> 2)) * 512 + gsrc * 8;
  const ushort* bgL = WtL + (size_t)(z * 512 + bn + wave * 64 + (lane >> 2)) * 512 + gsrc * 8;
  ushort* ldsH0 = &BsH[wave * 64][0];
  ushort* ldsL0 = &BsL[wave * 64][0];

  const int gq = (gk ^ ((fr >> 1) & 3)) * 8;   // frag-read granule (row bits 1..2 == fr bits 1..2)

  f32x4 acc[4][4];
#pragma unroll
  for (int m = 0; m < 4; ++m)
#pragma unroll
    for (int n = 0; n < 4; ++n)
#pragma unroll
      for (int j = 0; j < 4; ++j) acc[m][n][j] = 0.f;

  float4 af0 = *(const float4*)(xrow + 0);
  float4 af1 = *(const float4*)(xrow + 4);

  for (int k0 = 0; k0 < Dn; k0 += 32) {
    __syncthreads();   // previous iteration's LDS reads complete
    // B: issue async DMA for this k-step (4 chunks x {H,L})
#pragma unroll
    for (int c = 0; c < 4; ++c) {
      gload_lds16(bgH + k0 + c * 8192, ldsH0 + c * 512);   // 16 rows x 32 ushorts per chunk
      gload_lds16(bgL + k0 + c * 8192, ldsL0 + c * 512);
    }
    {
      // A: split 8 fp32 -> bf16 hi/lo granules, swizzled ds_write
      float xf[8] = {af0.x, af0.y, af0.z, af0.w, af1.x, af1.y, af1.z, af1.w};
      unsigned hp[4], lp[4];
#pragma unroll
      for (int i = 0; i < 8; i += 2) {
        const ushort h0 = bf16_rne(xf[i]), h1 = bf16_rne(xf[i + 1]);
        const ushort l0 = bf16_rne(xf[i] - bf16f(h0)), l1 = bf16_rne(xf[i + 1] - bf16f(h1));
        hp[i >> 1] = (unsigned)h0 | ((unsigned)h1 << 16);
        lp[i >> 1] = (unsigned)l0 | ((unsigned)l1 << 16);
      }
      *(uint4*)&AsH[ar][agq] = make_uint4(hp[0], hp[1], hp[2], hp[3]);
      *(uint4*)&AsL[ar][agq] = make_uint4(lp[0], lp[1], lp[2], lp[3]);
    }
    // prefetch next A regs (in flight across the barrier + MFMA)
    if (k0 + 32 < Dn) {
      af0 = *(const float4*)(xrow + k0 + 32);
      af1 = *(const float4*)(xrow + k0 + 36);
    }
    __syncthreads();   // drains vmcnt (B DMA) + lgkmcnt (A ds_write): tile ready

    short8 aH[4], aL[4], bH[4], bL[4];
#pragma unroll
    for (int m = 0; m < 4; ++m) {
      aH[m] = *(const short8*)&AsH[m * 16 + fr][gq];
      aL[m] = *(const short8*)&AsL[m * 16 + fr][gq];
    }
#pragma unroll
    for (int n = 0; n < 4; ++n) {
      bH[n] = *(const short8*)&BsH[wave * 64 + n * 16 + fr][gq];
      bL[n] = *(const short8*)&BsL[wave * 64 + n * 16 + fr][gq];
    }
#pragma unroll
    for (int m = 0; m < 4; ++m)
#pragma unroll
      for (int n = 0; n < 4; ++n) {
        MFMA(acc[m][n], aH[m], bH[n]);
        MFMA(acc[m][n], aH[m], bL[n]);
        MFMA(acc[m][n], aL[m], bH[n]);
      }
  }
  asm volatile("s_nop 7\n\ts_nop 7");   // MFMA->VALU hazard guard (inline-asm MFMA)

  float bsv[4];
#pragma unroll
  for (int n = 0; n < 4; ++n) bsv[n] = bias[bn + wave * 64 + n * 16 + fr];
#pragma unroll
  for (int m = 0; m < 4; ++m) {
#pragma unroll
    for (int n = 0; n < 4; ++n) {
      const int col = bn + wave * 64 + n * 16 + fr;   // C/D: col=lane&15, row=(lane>>4)*4+reg
#pragma unroll
      for (int j = 0; j < 4; ++j) {
        Y[(size_t)(bm + m * 16 + gk * 4 + j) * HDn + col] = acc[m][n][j] + bsv[n];
      }
    }
  }
}

// ------------- sampled launch: [0,64) v-mean partials; [64,8256) sampled M (row-major,
//               all 8 heads per row via segmented 8-lane reduce); [8256,...) light fill -------------
__global__ __launch_bounds__(64) void sampled_m_kernel(
    const float* __restrict__ q, const float* __restrict__ k,
    const int* __restrict__ idxs, float* __restrict__ Mt,
    const float* __restrict__ v, float* __restrict__ vpart,
    float* __restrict__ fscores) {
  const int bid = blockIdx.x;
  const int lane = threadIdx.x;

  if (bid >= NVPart + NSampled) {
    // fill 4 rows (32 KB) with 1/S; 64 threads -> 32 stores each
    const size_t r0 = (size_t)FillRowsS + (size_t)(bid - NVPart - NSampled) * 4;
    const float c = 1.0f / Sn;
    const f32x4 c4v = {c, c, c, c};
    f32x4* p = (f32x4*)fscores + r0 * (Sn / 4);
#pragma unroll
    for (int i = 0; i < 32; ++i) nt_store4(p + i * 64 + lane, c4v);
    return;
  }

  if (bid < NVPart) {
    // v-mean partials: 16 blocks per b, each sums 128 s-rows
    const int pb = bid;                    // 0..63
    const int b = pb >> 4, part = pb & 15;
    const float4* v4 = (const float4*)(v + (size_t)b * Sn * HDn);
    float4 a0 = make_float4(0.f, 0.f, 0.f, 0.f);
    float4 a1 = make_float4(0.f, 0.f, 0.f, 0.f);
    const int s0 = part * 128;
    for (int s = s0; s < s0 + 128; ++s) {
      const float4 x0 = v4[(size_t)s * 128 + lane * 2];
      const float4 x1 = v4[(size_t)s * 128 + lane * 2 + 1];
      a0.x += x0.x; a0.y += x0.y; a0.z += x0.z; a0.w += x0.w;
      a1.x += x1.x; a1.y += x1.y; a1.z += x1.z; a1.w += x1.w;
    }
    float4* vp4 = (float4*)vpart + (size_t)pb * 128;
    vp4[lane * 2] = a0; vp4[lane * 2 + 1] = a1;
    return;
  }

  // sampled M: lane l owns dims (l&7)*8..+8 of head l>>3; per sampled row all 64 lanes
  // read the full 2KB row contiguously; 3 shuffles give all 8 head-dots at once.
  // idxs[t*SKn+j] is block-uniform -> scalar loads, no LDS staging / barrier needed.
  const int inner = bid - NVPart;          // 0..8191
  const int b = inner >> 11, t = inner & (Tn - 1);

  const int* idxt = idxs + t * SKn;
  const float* qrow = q + ((size_t)(b * Tn + t)) * HDn + lane * 8;
  const float4 qv0 = *(const float4*)qrow;
  const float4 qv1 = *(const float4*)(qrow + 4);
  const float* kb = k + (size_t)b * Sn * HDn + lane * 8;

  float mx = -1e30f, sum = 0.f;
#pragma unroll 6
  for (int j = 0; j < SKn; ++j) {
    const float* kr = kb + (size_t)idxt[j] * HDn;
    const float4 kv0 = *(const float4*)kr;
    const float4 kv1 = *(const float4*)(kr + 4);
    float p = kv0.x * qv0.x + kv0.y * qv0.y + kv0.z * qv0.z + kv0.w * qv0.w
            + kv1.x * qv1.x + kv1.y * qv1.y + kv1.z * qv1.z + kv1.w * qv1.w;
    p += __shfl_xor(p, 1);
    p += __shfl_xor(p, 2);
    p += __shfl_xor(p, 4);   // all 8 lanes of the group now hold head (lane>>3)'s dot
    mx = fmaxf(mx, p);
    sum += p;
  }
  if ((lane & 7) == 0) {
    const int h = lane >> 3;
    Mt[((size_t)(b * Hn + h)) * Tn + t] = mx - sum * (1.0f / SKn);
  }
}

// ------------- fused: blocks 0..31 register-tournament top-30 per (b,h); 32..35 vmean+base per b;
//               blocks [36, ...) fill fscores rows [49152, 65536) on otherwise-idle CUs -------------
__global__ __launch_bounds__(256) void topk_vmean_base_kernel(
    const float* __restrict__ Mt, const float* __restrict__ vpart,
    const float* __restrict__ Wo, const float* __restrict__ bo,
    int* __restrict__ top, float* __restrict__ vmean, float* __restrict__ basep,
    float* __restrict__ fscores) {
  const int tid = threadIdx.x;
  const int lane = tid & 63, w = tid >> 6;

  if (blockIdx.x >= 36) {
    fill_rows4_256(fscores, (size_t)FillRowsT + (size_t)(blockIdx.x - 36) * 4, tid);
    return;
  }

  __shared__ float cval[128];
  __shared__ int cidx[128];
  __shared__ float4 part[256];
  __shared__ float vm[HDn];

  if (blockIdx.x < 32) {
    // top-30 of Mt[bh][0..2048): each wave holds its 512-value partition in registers,
    // selects its local top-30 barrier-free, then wave 0 merges 120 candidates.
    const int bh = blockIdx.x;
    if (tid < 128) { cval[tid] = -1e30f; cidx[tid] = -1; }
    __syncthreads();
    const float* mrow = Mt + (size_t)bh * Tn;
    const int base = w * 512 + lane;
    float rv[8];
#pragma unroll
    for (int j = 0; j < 8; ++j) rv[j] = mrow[base + j * 64];   // idx = base + j*64
    for (int u = 0; u < Un; ++u) {
      float bv = rv[0]; int bj = 0;
#pragma unroll
      for (int j = 1; j < 8; ++j) {
        if (rv[j] > bv) { bv = rv[j]; bj = j; }   // strict > keeps lowest idx on ties
      }
      int bi = base + bj * 64;
#pragma unroll
      for (int o = 1; o < 64; o <<= 1) {
        const float ov = __shfl_xor(bv, o);
        const int oi = __shfl_xor(bi, o);
        if (ov > bv || (ov == bv && oi < bi)) { bv = ov; bi = oi; }
      }
      // clear winner in its owner lane (static register indexing)
      if (((bi >> 9) == w) && ((bi & 63) == lane)) {
        const int bj2 = (bi >> 6) & 7;
#pragma unroll
        for (int j = 0; j < 8; ++j) {
          if (j == bj2) rv[j] = -1e30f;
        }
      }
      if (lane == 0) { cval[w * 32 + u] = bv; cidx[w * 32 + u] = bi; }
    }
    __syncthreads();
    if (w == 0) {
      float v0 = cval[lane], v1 = cval[64 + lane];
      int i0 = cidx[lane], i1 = cidx[64 + lane];
      for (int u = 0; u < Un; ++u) {
        float bv; int bi;
        if (v0 > v1 || (v0 == v1 && i0 < i1)) { bv = v0; bi = i0; }
        else { bv = v1; bi = i1; }
#pragma unroll
        for (int o = 1; o < 64; o <<= 1) {
          const float ov = __shfl_xor(bv, o);
          const int oi = __shfl_xor(bi, o);
          if (ov > bv || (ov == bv && oi < bi)) { bv = ov; bi = oi; }
        }
        if (i0 == bi) v0 = -1e30f;
        if (i1 == bi) v1 = -1e30f;
        if (lane == 0) top[bh * Un + u] = bi;
      }
    }
  } else {
    const int b = blockIdx.x - 32;
    const int c4 = tid & 127, half = tid >> 7;
    // combine the 16 precomputed partial sums
    float4 acc = make_float4(0.f, 0.f, 0.f, 0.f);
    for (int p = half * 8; p < half * 8 + 8; ++p) {
      const float4 x = ((const float4*)vpart)[(size_t)(b * 16 + p) * 128 + c4];
      acc.x += x.x; acc.y += x.y; acc.z += x.z; acc.w += x.w;
    }
    part[tid] = acc;
    __syncthreads();
    if (half == 0) {
      float4 a = part[c4], bpp = part[128 + c4];
      const float sc = 1.0f / Sn;
      float4 r = make_float4((a.x + bpp.x) * sc, (a.y + bpp.y) * sc,
                             (a.z + bpp.z) * sc, (a.w + bpp.w) * sc);
      *(float4*)(vm + c4 * 4) = r;
      *(float4*)(vmean + b * HDn + c4 * 4) = r;
    }
    __syncthreads();
    const float4* Wo4 = (const float4*)Wo;
    float4 acc2 = make_float4(0.f, 0.f, 0.f, 0.f);
    for (int c = half * 256; c < half * 256 + 256; ++c) {
      const float vmc = vm[c];
      const float4 wrow = Wo4[(size_t)c * 128 + c4];
      acc2.x += vmc * wrow.x; acc2.y += vmc * wrow.y;
      acc2.z += vmc * wrow.z; acc2.w += vmc * wrow.w;
    }
    __syncthreads();
    part[tid] = acc2;
    __syncthreads();
    if (half == 0) {
      float4 a = part[c4], bpp = part[128 + c4];
      const float4 bb = ((const float4*)bo)[c4];
      float4 r = make_float4(a.x + bpp.x + bb.x, a.y + bpp.y + bb.y,
                             a.z + bpp.z + bb.z, a.w + bpp.w + bb.w);
      ((float4*)basep)[b * 128 + c4] = r;
    }
  }
}

// ------------- mega B: [0,960) per-u attn (XCD b-clustered, Gu=1); [960,1984) out-base fill -------------
__global__ __launch_bounds__(256) void attn_out_kernel(
    const float* __restrict__ q, const float* __restrict__ k,
    const float* __restrict__ v, const float* __restrict__ vmean,
    const int* __restrict__ top, const float* __restrict__ Wo,
    const float* __restrict__ basep,
    float* __restrict__ out, float* __restrict__ fscores) {
  const int tid = threadIdx.x;
  const int bid = blockIdx.x;

  if (bid >= NAttnG) {
    // out base fill: 8 rows; plain store unless row is selected (then atomicAdd)
    const int fid = bid - NAttnG;               // 0..1023
    const int r0 = fid * 8;
    const int b = r0 >> 11;
    const int t0 = r0 & (Tn - 1);
    __shared__ int sflag8[8];
    if (tid < 8) sflag8[tid] = 0;
    __syncthreads();
    if (tid < Hn * Un) {                        // 240 entries for this b
      const int d = top[b * Hn * Un + tid] - t0;
      if (d >= 0 && d < 8) sflag8[d] = 1;
    }
    __syncthreads();
    const int col4 = tid & 127, rh = tid >> 7;
    const float4 bv4 = ((const float4*)basep)[b * 128 + col4];
    const f32x4 bvx = {bv4.x, bv4.y, bv4.z, bv4.w};
#pragma unroll
    for (int rp = 0; rp < 4; ++rp) {
      const int rr = rp * 2 + rh;
      float4* orow4 = (float4*)(out + (size_t)(r0 + rr) * HDn) + col4;
      if (sflag8[rr]) {
        float* p = (float*)orow4;
        atomicAdd(p + 0, bv4.x); atomicAdd(p + 1, bv4.y);
        atomicAdd(p + 2, bv4.z); atomicAdd(p + 3, bv4.w);
      } else {
        nt_store4((f32x4*)orow4, bvx);
      }
    }
    return;
  }

  // ---- per-u attention (Gu=1); XCD-clustered on b for k/v L2 locality ----
  const int xs = bid & 7;
  const int b = xs & 3;
  const int combo = (bid >> 3) + (xs >> 2) * 120;  // 0..239
  const int h = combo / NGroups;
  const int grp = combo % NGroups;
  const int bh = b * Hn + h;
  const int lane = tid & 63, w = tid >> 6;

  __shared__ float qs[DKn];            // reused later as delta
  __shared__ float sc[2052];           // padded: conflict-free access
  __shared__ float red[8];
  __shared__ int tsel0;
  __shared__ float4 partv[4][16];

  if (tid == 0) tsel0 = top[bh * Un + grp];
  __syncthreads();
  const int tsel = tsel0;
  if (tid < DKn) qs[tid] = q[((size_t)(b * Tn + tsel)) * HDn + h * DKn + tid];
  __syncthreads();

  // phase 1: scores, k row read once
  const float4* k4 = (const float4*)k;
  for (int s = tid; s < Sn; s += 256) {
    const float4* krow = k4 + ((size_t)(b * Sn + s)) * 128 + h * 16;
    float acc = 0.f;
#pragma unroll
    for (int d4i = 0; d4i < 16; ++d4i) {
      const float4 kv = krow[d4i];
      const float4 qv = *(const float4*)&qs[d4i * 4];
      acc += kv.x * qv.x + kv.y * qv.y + kv.z * qv.z + kv.w * qv.w;
    }
    sc[s] = acc * kScale;
  }
  __syncthreads();

  // phase 2: softmax
  float lm = -1e30f;
  for (int i = tid; i < Sn; i += 256) lm = fmaxf(lm, sc[i]);
#pragma unroll
  for (int o = 1; o < 64; o <<= 1) lm = fmaxf(lm, __shfl_xor(lm, o));
  if (lane == 0) red[w] = lm;
  __syncthreads();
  const float mx = fmaxf(fmaxf(red[0], red[1]), fmaxf(red[2], red[3]));
  float ls = 0.f;
  for (int i = tid; i < Sn; i += 256) {
    const float e = __expf(sc[i] - mx);
    sc[i] = e;
    ls += e;
  }
#pragma unroll
  for (int o = 1; o < 64; o <<= 1) ls += __shfl_xor(ls, o);
  if (lane == 0) red[4 + w] = ls;
  __syncthreads();
  const float inv = 1.0f / (red[4] + red[5] + red[6] + red[7]);
  // normalize + write fscores row (overwrites the 1/S fill from the earlier launches)
  {
    float4* scg4 = (float4*)sc;
    f32x4* fsrow4 = (f32x4*)(fscores + ((size_t)bh * Tn + tsel) * Sn);
#pragma unroll
    for (int it = 0; it < 2; ++it) {
      const int i = it * 256 + tid;
      float4 p = scg4[i];
      p.x *= inv; p.y *= inv; p.z *= inv; p.w *= inv;
      scg4[i] = p;
      const f32x4 px = {p.x, p.y, p.z, p.w};
      nt_store4(fsrow4 + i, px);
    }
  }
  __syncthreads();

  // phase 3: attn = scores @ v, v row read once
  const int d4 = lane & 15;
  const int sg = (w << 2) + (lane >> 4);   // 0..15
  const float4* v4 = (const float4*)v;
  float4 pacc = make_float4(0.f, 0.f, 0.f, 0.f);
  for (int s = sg; s < Sn; s += 16) {
    const float4 vv = v4[((size_t)(b * Sn + s)) * 128 + h * 16 + d4];
    const float p = sc[s];
    pacc.x += p * vv.x; pacc.y += p * vv.y;
    pacc.z += p * vv.z; pacc.w += p * vv.w;
  }
#pragma unroll
  for (int o = 16; o < 64; o <<= 1) {
    pacc.x += __shfl_xor(pacc.x, o);
    pacc.y += __shfl_xor(pacc.y, o);
    pacc.z += __shfl_xor(pacc.z, o);
    pacc.w += __shfl_xor(pacc.w, o);
  }
  if (lane < 16) partv[w][lane] = pacc;
  __syncthreads();
  if (tid < 16) {
    const int dd = tid;
    float4 r = partv[0][dd];
    const float4 r1 = partv[1][dd], r2 = partv[2][dd], r3 = partv[3][dd];
    r.x += r1.x + r2.x + r3.x; r.y += r1.y + r2.y + r3.y;
    r.z += r1.z + r2.z + r3.z; r.w += r1.w + r2.w + r3.w;
    const float4 vm4 = ((const float4*)vmean)[bh * 16 + dd];
    r.x -= vm4.x; r.y -= vm4.y; r.z -= vm4.z; r.w -= vm4.w;
    *(float4*)&qs[dd * 4] = r;           // qs reused as delta
  }
  __syncthreads();

  // phase 4: out row += delta @ Wo[h*64:(h+1)*64,:], 128 threads (same per-col math as before)
  if (tid < 128) {
    const int col4 = tid;
    const float4* Wo4 = (const float4*)Wo;
    float4 a = make_float4(0.f, 0.f, 0.f, 0.f);
#pragma unroll
    for (int d = 0; d < DKn; ++d) {
      const float dv = qs[d];
      const float4 wrow = Wo4[(size_t)(h * DKn + d) * 128 + col4];
      a.x += dv * wrow.x; a.y += dv * wrow.y;
      a.z += dv * wrow.z; a.w += dv * wrow.w;
    }
    float* orow = out + ((size_t)(b * Tn + tsel)) * HDn + col4 * 4;
    atomicAdd(orow + 0, a.x); atomicAdd(orow + 1, a.y);
    atomicAdd(orow + 2, a.z); atomicAdd(orow + 3, a.w);
  }
}

extern "C" void kernel_launch(void* const* d_in, const int* in_sizes, int n_in,
                              void* d_out, int out_size, void* d_ws, size_t ws_size,
                              hipStream_t stream) {
  const float* x_q = (const float*)d_in[0];
  const float* x_k = (const float*)d_in[1];
  const float* x_v = (const float*)d_in[2];
  const float* Wq = (const float*)d_in[3];
  const float* bq = (const float*)d_in[4];
  const float* Wk = (const float*)d_in[5];
  const float* bk = (const float*)d_in[6];
  const float* Wv = (const float*)d_in[7];
  const float* bv = (const float*)d_in[8];
  const float* Wo = (const float*)d_in[9];
  const float* bo = (const float*)d_in[10];
  const int* idx = (const int*)d_in[11];

  float* out = (float*)d_out;
  float* fscores = out + (size_t)Bn * Tn * HDn;

  float* ws = (float*)d_ws;
  float* q = ws;
  float* kp = ws + (size_t)4194304;
  float* vp = ws + (size_t)8388608;
  float* Mt = ws + (size_t)12582912;
  float* vmean = ws + (size_t)12648448;
  float* basep = ws + (size_t)12650496;
  int* top = (int*)(ws + (size_t)12652544);
  float* vpart = ws + (size_t)12656640;   // 64*512 floats

  // W-split scratch in the fscores tail rows [49152, 65536): written by prep, read by gemm,
  // then overwritten by fill blocks of the topk launch (strictly after gemm).
  char* scr = (char*)(fscores + (size_t)49152 * Sn);
  ushort* WtH = (ushort*)scr;
  ushort* WtL = WtH + (size_t)3 * 512 * 512;

  // 0) transpose+split W into bf16 hi/lo (tiny)
  prep_split_kernel<<<NWsplit, 256, 0, stream>>>(Wq, Wk, Wv, WtH, WtL);

  // 1) q/k/v projections (MFMA bf16x3, B via global_load_lds) + fill rows [0,40960)
  gemm_fill_kernel<<<NGemm + NFillG, 256, 0, stream>>>(
      x_q, x_k, x_v, WtH, WtL, bq, bk, bv, q, kp, vp, fscores);

  // 2) v-mean partials + sampled scores -> M (row-major all-heads) + light fill [40960,49152)
  sampled_m_kernel<<<NVPart + NSampled + NFillS, 64, 0, stream>>>(
      q, kp, idx, Mt, vp, vpart, fscores);

  // 3) register-tournament top-30 + v_mean(from partials) + base row + fill rows [49152,65536)
  topk_vmean_base_kernel<<<36 + NFillT, 256, 0, stream>>>(
      Mt, vpart, Wo, bo, top, vmean, basep, fscores);

  // 4) per-u attention (Gu=1, 960 blocks) + out base fill
  attn_out_kernel<<<NAttnG + NOutF, 256, 0, stream>>>(
      q, kp, vp, vmean, top, Wo, basep, out, fscores);
}

// Round 9
// 749.920 us; speedup vs baseline: 1.0485x; 1.0485x over previous
//
#include <hip/hip_runtime.h>

typedef __attribute__((ext_vector_type(8))) short short8;
typedef __attribute__((ext_vector_type(4))) float f32x4;

constexpr int Bn  = 4;
constexpr int Tn  = 2048;
constexpr int Sn  = 2048;
constexpr int Dn  = 512;
constexpr int Hn  = 8;
constexpr int DKn = 64;
constexpr int DVn = 64;
constexpr int HDn = 512;   // H*DK = H*DV
constexpr int SKn = 30;    // sample_k
constexpr int Un  = 30;    // top-u
constexpr int Gu  = 2;     // u's per attention block (Gu=2 sweet spot: R7=752 vs Gu=1 R8=786)
constexpr int NGroups = Un / Gu;            // 15
constexpr int NAttnG  = Bn * Hn * NGroups;  // 480 attention blocks
constexpr int NOutF   = (Bn * Tn) / 8;      // 1024 out-base blocks (8 rows each)
constexpr int NGemm  = 768;                 // 3 z x 128 m-blocks x 2 n-blocks
constexpr float kScale = 0.125f;            // 1/sqrt(DK)

constexpr int NWsplit = 192;    // W transpose+split blocks
constexpr int NVPart  = 64;     // v-mean partial blocks (prefix of sampled launch)
constexpr int NSampled = Bn * Tn;           // 8192

// fscores fill distribution (R7-proven): keep the latency-bound sampled segment nearly fill-free.
constexpr int NFillG = 9216;    // gemm launch: rows [0, 36864)
constexpr int NFillS = 2048;    // sampled launch: rows [36864, 45056)
constexpr int NFillT = 5120;    // topk launch: rows [45056, 65536) (covers Wt scratch: after gemm)
constexpr int FillRowsG = 0;
constexpr int FillRowsS = NFillG * 4;             // 36864
constexpr int FillRowsT = (NFillG + NFillS) * 4;  // 45056

__device__ __forceinline__ ushort bf16_rne(float x) {
  unsigned u = __float_as_uint(x);
  return (ushort)((u + 0x7fffu + ((u >> 16) & 1u)) >> 16);
}
__device__ __forceinline__ float bf16f(ushort h) {
  return __uint_as_float(((unsigned)h) << 16);
}
__device__ __forceinline__ void nt_store4(f32x4* p, f32x4 v) {
  __builtin_nontemporal_store(v, p);
}
__device__ __forceinline__ void fill_rows4_256(float* fscores, size_t r0, int tid) {
  const float c = 1.0f / Sn;
  const f32x4 c4v = {c, c, c, c};
  f32x4* fs4 = (f32x4*)fscores + r0 * (Sn / 4);
#pragma unroll
  for (int i = 0; i < 8; ++i) nt_store4(fs4 + i * 256 + tid, c4v);
}
// async global->LDS DMA, 16B per lane; LDS dest = base + lane*16 (wave-uniform base)
__device__ __forceinline__ void gload_lds16(const void* g, void* lds) {
  __builtin_amdgcn_global_load_lds((const __attribute__((address_space(1))) void*)g,
                                   (__attribute__((address_space(3))) void*)lds, 16, 0, 0);
}

#define MFMA(accv, av, bv) \
  asm volatile("v_mfma_f32_16x16x32_bf16 %0, %1, %2, %0" : "+v"(accv) : "v"(av), "v"(bv))

// ------------- prep: transpose+split W into bf16 hi/lo (W is tiny: 3 MB, stays L2/L3 resident) -------------
__global__ __launch_bounds__(256) void prep_split_kernel(
    const float* __restrict__ Wq, const float* __restrict__ Wk, const float* __restrict__ Wv,
    ushort* __restrict__ WtH, ushort* __restrict__ WtL) {
  const int tid = threadIdx.x;
  const int bid = blockIdx.x;

  // W[k][n] -> Wt[n][k], split into bf16 hi/lo
  const int z = bid / 64, t = bid % 64;
  const int k0 = (t >> 3) * 64, n0 = (t & 7) * 64;
  const float* W = (z == 0) ? Wq : (z == 1) ? Wk : Wv;
  __shared__ float tile[64][65];
  const int r = tid >> 2, c0 = (tid & 3) * 16;
#pragma unroll
  for (int i = 0; i < 16; i += 4) {
    const float4 vv = *(const float4*)(W + (size_t)(k0 + r) * HDn + n0 + c0 + i);
    tile[r][c0 + i] = vv.x; tile[r][c0 + i + 1] = vv.y;
    tile[r][c0 + i + 2] = vv.z; tile[r][c0 + i + 3] = vv.w;
  }
  __syncthreads();
  unsigned hp[8], lp[8];
#pragma unroll
  for (int i = 0; i < 16; i += 2) {
    const float x0 = tile[c0 + i][r];
    const float x1 = tile[c0 + i + 1][r];
    const ushort h0 = bf16_rne(x0), h1 = bf16_rne(x1);
    const ushort l0 = bf16_rne(x0 - bf16f(h0)), l1 = bf16_rne(x1 - bf16f(h1));
    hp[i >> 1] = (unsigned)h0 | ((unsigned)h1 << 16);
    lp[i >> 1] = (unsigned)l0 | ((unsigned)l1 << 16);
  }
  const size_t off = (size_t)(z * 512 + n0 + r) * 512 + k0 + c0;
  *(uint4*)(WtH + off)     = make_uint4(hp[0], hp[1], hp[2], hp[3]);
  *(uint4*)(WtH + off + 8) = make_uint4(hp[4], hp[5], hp[6], hp[7]);
  *(uint4*)(WtL + off)     = make_uint4(lp[0], lp[1], lp[2], lp[3]);
  *(uint4*)(WtL + off + 8) = make_uint4(lp[4], lp[5], lp[6], lp[7]);
}

// ------------- mega A: blocks[0..767] MFMA bf16x3 q/k/v GEMM (A split in-kernel; B via
//               global_load_lds DMA with source-side swizzle); rest fill fscores [0,36864) -------------
__global__ __launch_bounds__(256, 2) void gemm_fill_kernel(
    const float* __restrict__ xq, const float* __restrict__ xk, const float* __restrict__ xv,
    const ushort* __restrict__ WtH, const ushort* __restrict__ WtL,
    const float* __restrict__ bq, const float* __restrict__ bk, const float* __restrict__ bv,
    float* __restrict__ qo, float* __restrict__ ko, float* __restrict__ vo,
    float* __restrict__ fscores) {
  const int bid = blockIdx.x;
  const int tid = threadIdx.x;

  if (bid >= NGemm) {
    fill_rows4_256(fscores, (size_t)FillRowsG + (size_t)(bid - NGemm) * 4, tid);
    return;
  }

  // LDS: granule-XOR swizzled (granule = 8 ushorts = 16B): slot s of row n holds source
  // granule s ^ ((n>>1)&3). A: via swizzled ds_write. B: via DMA with swizzled SOURCE addr.
  __shared__ ushort AsH[64][32];    // 4 KB
  __shared__ ushort AsL[64][32];
  __shared__ ushort BsH[256][32];   // 16 KB
  __shared__ ushort BsL[256][32];   // total 40 KB

  const int z = bid >> 8;            // 0..2 selects q/k/v
  const int rem = bid & 255;
  const int bm = (rem >> 1) * 64;    // 64-row A block
  const int bn = (rem & 1) * 256;    // 256-col B block
  const float* X = (z == 0) ? xq : (z == 1) ? xk : xv;
  const float* bias = (z == 0) ? bq : (z == 1) ? bk : bv;
  float* Y = (z == 0) ? qo : (z == 1) ? ko : vo;

  const int lane = tid & 63;
  const int wave = tid >> 6;                 // wave tile: 64m x 64n
  const int fr = lane & 15;                  // fragment row/col
  const int gk = lane >> 4;                  // k-granule 0..3 within 32

  // A staging: thread loads row ar, k-granule ag (8 fp32 = 32B)
  const int ar = tid >> 2, ag = tid & 3;
  const float* xrow = X + (size_t)(bm + ar) * Dn + ag * 8;
  const int agq = (ag ^ ((ar >> 1) & 3)) * 8;

  // B staging via DMA: wave w covers rows [w*64, w*64+64) of BsH/BsL in 4 chunks of 16 rows.
  // lane l -> row chunkBase + (l>>2), LDS slot (l&3); source granule = (l&3)^((l>>3)&3)
  // (== slot ^ ((row>>1)&3) since chunkBase is a multiple of 16).
  const int gsrc = (lane & 3) ^ ((lane >> 3) & 3);
  const ushort* bgH = WtH + (size_t)(z * 512 + bn + wave * 64 + (lane >> 2)) * 512 + gsrc * 8;
  const ushort* bgL = WtL + (size_t)(z * 512 + bn + wave * 64 + (lane >> 2)) * 512 + gsrc * 8;
  ushort* ldsH0 = &BsH[wave * 64][0];
  ushort* ldsL0 = &BsL[wave * 64][0];

  const int gq = (gk ^ ((fr >> 1) & 3)) * 8;   // frag-read granule (row bits 1..2 == fr bits 1..2)

  f32x4 acc[4][4];
#pragma unroll
  for (int m = 0; m < 4; ++m)
#pragma unroll
    for (int n = 0; n < 4; ++n)
#pragma unroll
      for (int j = 0; j < 4; ++j) acc[m][n][j] = 0.f;

  float4 af0 = *(const float4*)(xrow + 0);
  float4 af1 = *(const float4*)(xrow + 4);

  for (int k0 = 0; k0 < Dn; k0 += 32) {
    __syncthreads();   // previous iteration's LDS reads complete
    // B: issue async DMA for this k-step (4 chunks x {H,L})
#pragma unroll
    for (int c = 0; c < 4; ++c) {
      gload_lds16(bgH + k0 + c * 8192, ldsH0 + c * 512);   // 16 rows x 32 ushorts per chunk
      gload_lds16(bgL + k0 + c * 8192, ldsL0 + c * 512);
    }
    {
      // A: split 8 fp32 -> bf16 hi/lo granules, swizzled ds_write
      float xf[8] = {af0.x, af0.y, af0.z, af0.w, af1.x, af1.y, af1.z, af1.w};
      unsigned hp[4], lp[4];
#pragma unroll
      for (int i = 0; i < 8; i += 2) {
        const ushort h0 = bf16_rne(xf[i]), h1 = bf16_rne(xf[i + 1]);
        const ushort l0 = bf16_rne(xf[i] - bf16f(h0)), l1 = bf16_rne(xf[i + 1] - bf16f(h1));
        hp[i >> 1] = (unsigned)h0 | ((unsigned)h1 << 16);
        lp[i >> 1] = (unsigned)l0 | ((unsigned)l1 << 16);
      }
      *(uint4*)&AsH[ar][agq] = make_uint4(hp[0], hp[1], hp[2], hp[3]);
      *(uint4*)&AsL[ar][agq] = make_uint4(lp[0], lp[1], lp[2], lp[3]);
    }
    // prefetch next A regs (in flight across the barrier + MFMA)
    if (k0 + 32 < Dn) {
      af0 = *(const float4*)(xrow + k0 + 32);
      af1 = *(const float4*)(xrow + k0 + 36);
    }
    __syncthreads();   // drains vmcnt (B DMA) + lgkmcnt (A ds_write): tile ready

    short8 aH[4], aL[4], bH[4], bL[4];
#pragma unroll
    for (int m = 0; m < 4; ++m) {
      aH[m] = *(const short8*)&AsH[m * 16 + fr][gq];
      aL[m] = *(const short8*)&AsL[m * 16 + fr][gq];
    }
#pragma unroll
    for (int n = 0; n < 4; ++n) {
      bH[n] = *(const short8*)&BsH[wave * 64 + n * 16 + fr][gq];
      bL[n] = *(const short8*)&BsL[wave * 64 + n * 16 + fr][gq];
    }
#pragma unroll
    for (int m = 0; m < 4; ++m)
#pragma unroll
      for (int n = 0; n < 4; ++n) {
        MFMA(acc[m][n], aH[m], bH[n]);
        MFMA(acc[m][n], aH[m], bL[n]);
        MFMA(acc[m][n], aL[m], bH[n]);
      }
  }
  asm volatile("s_nop 7\n\ts_nop 7");   // MFMA->VALU hazard guard (inline-asm MFMA)

  float bsv[4];
#pragma unroll
  for (int n = 0; n < 4; ++n) bsv[n] = bias[bn + wave * 64 + n * 16 + fr];
#pragma unroll
  for (int m = 0; m < 4; ++m) {
#pragma unroll
    for (int n = 0; n < 4; ++n) {
      const int col = bn + wave * 64 + n * 16 + fr;   // C/D: col=lane&15, row=(lane>>4)*4+reg
#pragma unroll
      for (int j = 0; j < 4; ++j) {
        Y[(size_t)(bm + m * 16 + gk * 4 + j) * HDn + col] = acc[m][n][j] + bsv[n];
      }
    }
  }
}

// ------------- sampled launch: [0,64) v-mean partials; [64,8256) sampled M (row-major,
//               all 8 heads per row via segmented 8-lane reduce); [8256,...) light fill -------------
__global__ __launch_bounds__(64) void sampled_m_kernel(
    const float* __restrict__ q, const float* __restrict__ k,
    const int* __restrict__ idxs, float* __restrict__ Mt,
    const float* __restrict__ v, float* __restrict__ vpart,
    float* __restrict__ fscores) {
  const int bid = blockIdx.x;
  const int lane = threadIdx.x;

  if (bid >= NVPart + NSampled) {
    // fill 4 rows (32 KB) with 1/S; 64 threads -> 32 stores each
    const size_t r0 = (size_t)FillRowsS + (size_t)(bid - NVPart - NSampled) * 4;
    const float c = 1.0f / Sn;
    const f32x4 c4v = {c, c, c, c};
    f32x4* p = (f32x4*)fscores + r0 * (Sn / 4);
#pragma unroll
    for (int i = 0; i < 32; ++i) nt_store4(p + i * 64 + lane, c4v);
    return;
  }

  if (bid < NVPart) {
    // v-mean partials: 16 blocks per b, each sums 128 s-rows
    const int pb = bid;                    // 0..63
    const int b = pb >> 4, part = pb & 15;
    const float4* v4 = (const float4*)(v + (size_t)b * Sn * HDn);
    float4 a0 = make_float4(0.f, 0.f, 0.f, 0.f);
    float4 a1 = make_float4(0.f, 0.f, 0.f, 0.f);
    const int s0 = part * 128;
    for (int s = s0; s < s0 + 128; ++s) {
      const float4 x0 = v4[(size_t)s * 128 + lane * 2];
      const float4 x1 = v4[(size_t)s * 128 + lane * 2 + 1];
      a0.x += x0.x; a0.y += x0.y; a0.z += x0.z; a0.w += x0.w;
      a1.x += x1.x; a1.y += x1.y; a1.z += x1.z; a1.w += x1.w;
    }
    float4* vp4 = (float4*)vpart + (size_t)pb * 128;
    vp4[lane * 2] = a0; vp4[lane * 2 + 1] = a1;
    return;
  }

  // sampled M: lane l owns dims (l&7)*8..+8 of head l>>3; per sampled row all 64 lanes
  // read the full 2KB row contiguously; 3 shuffles give all 8 head-dots at once.
  // idxs[t*SKn+j] is block-uniform -> scalar loads, no LDS staging / barrier needed.
  const int inner = bid - NVPart;          // 0..8191
  const int b = inner >> 11, t = inner & (Tn - 1);

  const int* idxt = idxs + t * SKn;
  const float* qrow = q + ((size_t)(b * Tn + t)) * HDn + lane * 8;
  const float4 qv0 = *(const float4*)qrow;
  const float4 qv1 = *(const float4*)(qrow + 4);
  const float* kb = k + (size_t)b * Sn * HDn + lane * 8;

  float mx = -1e30f, sum = 0.f;
#pragma unroll 6
  for (int j = 0; j < SKn; ++j) {
    const float* kr = kb + (size_t)idxt[j] * HDn;
    const float4 kv0 = *(const float4*)kr;
    const float4 kv1 = *(const float4*)(kr + 4);
    float p = kv0.x * qv0.x + kv0.y * qv0.y + kv0.z * qv0.z + kv0.w * qv0.w
            + kv1.x * qv1.x + kv1.y * qv1.y + kv1.z * qv1.z + kv1.w * qv1.w;
    p += __shfl_xor(p, 1);
    p += __shfl_xor(p, 2);
    p += __shfl_xor(p, 4);   // all 8 lanes of the group now hold head (lane>>3)'s dot
    mx = fmaxf(mx, p);
    sum += p;
  }
  if ((lane & 7) == 0) {
    const int h = lane >> 3;
    Mt[((size_t)(b * Hn + h)) * Tn + t] = mx - sum * (1.0f / SKn);
  }
}

// ------------- fused: blocks 0..31 register-tournament top-30 per (b,h); 32..35 vmean+base per b;
//               blocks [36, ...) fill fscores rows [45056, 65536) on otherwise-idle CUs -------------
__global__ __launch_bounds__(256) void topk_vmean_base_kernel(
    const float* __restrict__ Mt, const float* __restrict__ vpart,
    const float* __restrict__ Wo, const float* __restrict__ bo,
    int* __restrict__ top, float* __restrict__ vmean, float* __restrict__ basep,
    float* __restrict__ fscores) {
  const int tid = threadIdx.x;
  const int lane = tid & 63, w = tid >> 6;

  if (blockIdx.x >= 36) {
    fill_rows4_256(fscores, (size_t)FillRowsT + (size_t)(blockIdx.x - 36) * 4, tid);
    return;
  }

  __shared__ float cval[128];
  __shared__ int cidx[128];
  __shared__ float4 part[256];
  __shared__ float vm[HDn];

  if (blockIdx.x < 32) {
    // top-30 of Mt[bh][0..2048): each wave holds its 512-value partition in registers,
    // selects its local top-30 barrier-free, then wave 0 merges 120 candidates.
    // (verified correct in R8: identical top[] / absmax)
    const int bh = blockIdx.x;
    if (tid < 128) { cval[tid] = -1e30f; cidx[tid] = -1; }
    __syncthreads();
    const float* mrow = Mt + (size_t)bh * Tn;
    const int base = w * 512 + lane;
    float rv[8];
#pragma unroll
    for (int j = 0; j < 8; ++j) rv[j] = mrow[base + j * 64];   // idx = base + j*64
    for (int u = 0; u < Un; ++u) {
      float bv = rv[0]; int bj = 0;
#pragma unroll
      for (int j = 1; j < 8; ++j) {
        if (rv[j] > bv) { bv = rv[j]; bj = j; }   // strict > keeps lowest idx on ties
      }
      int bi = base + bj * 64;
#pragma unroll
      for (int o = 1; o < 64; o <<= 1) {
        const float ov = __shfl_xor(bv, o);
        const int oi = __shfl_xor(bi, o);
        if (ov > bv || (ov == bv && oi < bi)) { bv = ov; bi = oi; }
      }
      // clear winner in its owner lane (static register indexing)
      if (((bi >> 9) == w) && ((bi & 63) == lane)) {
        const int bj2 = (bi >> 6) & 7;
#pragma unroll
        for (int j = 0; j < 8; ++j) {
          if (j == bj2) rv[j] = -1e30f;
        }
      }
      if (lane == 0) { cval[w * 32 + u] = bv; cidx[w * 32 + u] = bi; }
    }
    __syncthreads();
    if (w == 0) {
      float v0 = cval[lane], v1 = cval[64 + lane];
      int i0 = cidx[lane], i1 = cidx[64 + lane];
      for (int u = 0; u < Un; ++u) {
        float bv; int bi;
        if (v0 > v1 || (v0 == v1 && i0 < i1)) { bv = v0; bi = i0; }
        else { bv = v1; bi = i1; }
#pragma unroll
        for (int o = 1; o < 64; o <<= 1) {
          const float ov = __shfl_xor(bv, o);
          const int oi = __shfl_xor(bi, o);
          if (ov > bv || (ov == bv && oi < bi)) { bv = ov; bi = oi; }
        }
        if (i0 == bi) v0 = -1e30f;
        if (i1 == bi) v1 = -1e30f;
        if (lane == 0) top[bh * Un + u] = bi;
      }
    }
  } else {
    const int b = blockIdx.x - 32;
    const int c4 = tid & 127, half = tid >> 7;
    // combine the 16 precomputed partial sums
    float4 acc = make_float4(0.f, 0.f, 0.f, 0.f);
    for (int p = half * 8; p < half * 8 + 8; ++p) {
      const float4 x = ((const float4*)vpart)[(size_t)(b * 16 + p) * 128 + c4];
      acc.x += x.x; acc.y += x.y; acc.z += x.z; acc.w += x.w;
    }
    part[tid] = acc;
    __syncthreads();
    if (half == 0) {
      float4 a = part[c4], bpp = part[128 + c4];
      const float sc = 1.0f / Sn;
      float4 r = make_float4((a.x + bpp.x) * sc, (a.y + bpp.y) * sc,
                             (a.z + bpp.z) * sc, (a.w + bpp.w) * sc);
      *(float4*)(vm + c4 * 4) = r;
      *(float4*)(vmean + b * HDn + c4 * 4) = r;
    }
    __syncthreads();
    const float4* Wo4 = (const float4*)Wo;
    float4 acc2 = make_float4(0.f, 0.f, 0.f, 0.f);
    for (int c = half * 256; c < half * 256 + 256; ++c) {
      const float vmc = vm[c];
      const float4 wrow = Wo4[(size_t)c * 128 + c4];
      acc2.x += vmc * wrow.x; acc2.y += vmc * wrow.y;
      acc2.z += vmc * wrow.z; acc2.w += vmc * wrow.w;
    }
    __syncthreads();
    part[tid] = acc2;
    __syncthreads();
    if (half == 0) {
      float4 a = part[c4], bpp = part[128 + c4];
      const float4 bb = ((const float4*)bo)[c4];
      float4 r = make_float4(a.x + bpp.x + bb.x, a.y + bpp.y + bb.y,
                             a.z + bpp.z + bb.z, a.w + bpp.w + bb.w);
      ((float4*)basep)[b * 128 + c4] = r;
    }
  }
}

// ------------- mega B: [0,480) grouped attn (XCD b-clustered, Gu=2); [480,1504) out-base fill -------------
__global__ __launch_bounds__(256) void attn_out_kernel(
    const float* __restrict__ q, const float* __restrict__ k,
    const float* __restrict__ v, const float* __restrict__ vmean,
    const int* __restrict__ top, const float* __restrict__ Wo,
    const float* __restrict__ basep,
    float* __restrict__ out, float* __restrict__ fscores) {
  const int tid = threadIdx.x;
  const int bid = blockIdx.x;

  if (bid >= NAttnG) {
    // out base fill: 8 rows; plain store unless row is selected (then atomicAdd)
    const int fid = bid - NAttnG;               // 0..1023
    const int r0 = fid * 8;
    const int b = r0 >> 11;
    const int t0 = r0 & (Tn - 1);
    __shared__ int sflag8[8];
    if (tid < 8) sflag8[tid] = 0;
    __syncthreads();
    if (tid < Hn * Un) {                        // 240 entries for this b
      const int d = top[b * Hn * Un + tid] - t0;
      if (d >= 0 && d < 8) sflag8[d] = 1;
    }
    __syncthreads();
    const int col4 = tid & 127, rh = tid >> 7;
    const float4 bv4 = ((const float4*)basep)[b * 128 + col4];
    const f32x4 bvx = {bv4.x, bv4.y, bv4.z, bv4.w};
#pragma unroll
    for (int rp = 0; rp < 4; ++rp) {
      const int rr = rp * 2 + rh;
      float4* orow4 = (float4*)(out + (size_t)(r0 + rr) * HDn) + col4;
      if (sflag8[rr]) {
        float* p = (float*)orow4;
        atomicAdd(p + 0, bv4.x); atomicAdd(p + 1, bv4.y);
        atomicAdd(p + 2, bv4.z); atomicAdd(p + 3, bv4.w);
      } else {
        nt_store4((f32x4*)orow4, bvx);
      }
    }
    return;
  }

  // ---- grouped attention: Gu=2 u's per block; XCD-clustered on b for k/v L2 locality ----
  const int xs = bid & 7;
  const int b = xs & 3;
  const int combo = (bid >> 3) + (xs >> 2) * 60;   // 0..119
  const int h = combo / NGroups;
  const int grp = combo % NGroups;
  const int bh = b * Hn + h;
  const int u0 = grp * Gu;
  const int lane = tid & 63, w = tid >> 6;

  __shared__ float qs[Gu][DKn];        // reused later as delta
  __shared__ float sc[Gu][2052];       // padded: conflict-free column access
  __shared__ float red[8];
  __shared__ int tsel[Gu];
  __shared__ float4 partv[4][Gu][16];

  if (tid < Gu) tsel[tid] = top[bh * Un + u0 + tid];
  __syncthreads();
  if (tid < Gu * DKn) {
    const int g = tid >> 6, d = tid & 63;
    qs[g][d] = q[((size_t)(b * Tn + tsel[g])) * HDn + h * DKn + d];
  }
  __syncthreads();

  // phase 1: scores for both u's, k row read once
  const float4* k4 = (const float4*)k;
  for (int s = tid; s < Sn; s += 256) {
    const float4* krow = k4 + ((size_t)(b * Sn + s)) * 128 + h * 16;
    float acc[Gu];
#pragma unroll
    for (int g = 0; g < Gu; ++g) acc[g] = 0.f;
#pragma unroll
    for (int d4i = 0; d4i < 16; ++d4i) {
      const float4 kv = krow[d4i];
#pragma unroll
      for (int g = 0; g < Gu; ++g) {
        const float4 qv = *(const float4*)&qs[g][d4i * 4];
        acc[g] += kv.x * qv.x + kv.y * qv.y + kv.z * qv.z + kv.w * qv.w;
      }
    }
#pragma unroll
    for (int g = 0; g < Gu; ++g) sc[g][s] = acc[g] * kScale;
  }
  __syncthreads();

  // phase 2: softmax per u
  float invs[Gu];
#pragma unroll
  for (int g = 0; g < Gu; ++g) {
    float lm = -1e30f;
    for (int i = tid; i < Sn; i += 256) lm = fmaxf(lm, sc[g][i]);
#pragma unroll
    for (int o = 1; o < 64; o <<= 1) lm = fmaxf(lm, __shfl_xor(lm, o));
    if (lane == 0) red[w] = lm;
    __syncthreads();
    const float mx = fmaxf(fmaxf(red[0], red[1]), fmaxf(red[2], red[3]));
    float ls = 0.f;
    for (int i = tid; i < Sn; i += 256) {
      const float e = __expf(sc[g][i] - mx);
      sc[g][i] = e;
      ls += e;
    }
#pragma unroll
    for (int o = 1; o < 64; o <<= 1) ls += __shfl_xor(ls, o);
    if (lane == 0) red[4 + w] = ls;
    __syncthreads();
    invs[g] = 1.0f / (red[4] + red[5] + red[6] + red[7]);
    __syncthreads();   // WAR on red[] before next g
  }
  // normalize + write fscores rows (overwrites the 1/S fill from the earlier launches)
#pragma unroll
  for (int g = 0; g < Gu; ++g) {
    const float inv = invs[g];
    float4* scg4 = (float4*)sc[g];
    f32x4* fsrow4 = (f32x4*)(fscores + ((size_t)bh * Tn + tsel[g]) * Sn);
#pragma unroll
    for (int it = 0; it < 2; ++it) {
      const int i = it * 256 + tid;
      float4 p = scg4[i];
      p.x *= inv; p.y *= inv; p.z *= inv; p.w *= inv;
      scg4[i] = p;
      const f32x4 px = {p.x, p.y, p.z, p.w};
      nt_store4(fsrow4 + i, px);
    }
  }
  __syncthreads();

  // phase 3: attn = scores @ v, v row read once
  const int d4 = lane & 15;
  const int sg = (w << 2) + (lane >> 4);   // 0..15
  const float4* v4 = (const float4*)v;
  float4 pacc[Gu];
#pragma unroll
  for (int g = 0; g < Gu; ++g) pacc[g] = make_float4(0.f, 0.f, 0.f, 0.f);
  for (int s = sg; s < Sn; s += 16) {
    const float4 vv = v4[((size_t)(b * Sn + s)) * 128 + h * 16 + d4];
#pragma unroll
    for (int g = 0; g < Gu; ++g) {
      const float p = sc[g][s];
      pacc[g].x += p * vv.x; pacc[g].y += p * vv.y;
      pacc[g].z += p * vv.z; pacc[g].w += p * vv.w;
    }
  }
#pragma unroll
  for (int g = 0; g < Gu; ++g) {
#pragma unroll
    for (int o = 16; o < 64; o <<= 1) {
      pacc[g].x += __shfl_xor(pacc[g].x, o);
      pacc[g].y += __shfl_xor(pacc[g].y, o);
      pacc[g].z += __shfl_xor(pacc[g].z, o);
      pacc[g].w += __shfl_xor(pacc[g].w, o);
    }
    if (lane < 16) partv[w][g][lane] = pacc[g];
  }
  __syncthreads();
  if (tid < Gu * 16) {
    const int g = tid >> 4, dd = tid & 15;
    float4 r = partv[0][g][dd];
    const float4 r1 = partv[1][g][dd], r2 = partv[2][g][dd], r3 = partv[3][g][dd];
    r.x += r1.x + r2.x + r3.x; r.y += r1.y + r2.y + r3.y;
    r.z += r1.z + r2.z + r3.z; r.w += r1.w + r2.w + r3.w;
    const float4 vm4 = ((const float4*)vmean)[bh * 16 + dd];
    r.x -= vm4.x; r.y -= vm4.y; r.z -= vm4.z; r.w -= vm4.w;
    *(float4*)&qs[g][dd * 4] = r;      // qs reused as delta
  }
  __syncthreads();

  // phase 4: out rows += delta @ Wo[h*64:(h+1)*64,:], both u's in parallel (128 threads each)
  const int col4 = tid & 127, g = tid >> 7;
  const float4* Wo4 = (const float4*)Wo;
  {
    float4 a = make_float4(0.f, 0.f, 0.f, 0.f);
#pragma unroll
    for (int d = 0; d < DKn; ++d) {
      const float dv = qs[g][d];
      const float4 wrow = Wo4[(size_t)(h * DKn + d) * 128 + col4];
      a.x += dv * wrow.x; a.y += dv * wrow.y;
      a.z += dv * wrow.z; a.w += dv * wrow.w;
    }
    float* orow = out + ((size_t)(b * Tn + tsel[g])) * HDn + col4 * 4;
    atomicAdd(orow + 0, a.x); atomicAdd(orow + 1, a.y);
    atomicAdd(orow + 2, a.z); atomicAdd(orow + 3, a.w);
  }
}

extern "C" void kernel_launch(void* const* d_in, const int* in_sizes, int n_in,
                              void* d_out, int out_size, void* d_ws, size_t ws_size,
                              hipStream_t stream) {
  const float* x_q = (const float*)d_in[0];
  const float* x_k = (const float*)d_in[1];
  const float* x_v = (const float*)d_in[2];
  const float* Wq = (const float*)d_in[3];
  const float* bq = (const float*)d_in[4];
  const float* Wk = (const float*)d_in[5];
  const float* bk = (const float*)d_in[6];
  const float* Wv = (const float*)d_in[7];
  const float* bv = (const float*)d_in[8];
  const float* Wo = (const float*)d_in[9];
  const float* bo = (const float*)d_in[10];
  const int* idx = (const int*)d_in[11];

  float* out = (float*)d_out;
  float* fscores = out + (size_t)Bn * Tn * HDn;

  float* ws = (float*)d_ws;
  float* q = ws;
  float* kp = ws + (size_t)4194304;
  float* vp = ws + (size_t)8388608;
  float* Mt = ws + (size_t)12582912;
  float* vmean = ws + (size_t)12648448;
  float* basep = ws + (size_t)12650496;
  int* top = (int*)(ws + (size_t)12652544);
  float* vpart = ws + (size_t)12656640;   // 64*512 floats

  // W-split scratch in the fscores tail rows [49152, 65536): written by prep, read by gemm,
  // then overwritten by fill blocks of the topk launch (strictly after gemm).
  char* scr = (char*)(fscores + (size_t)49152 * Sn);
  ushort* WtH = (ushort*)scr;
  ushort* WtL = WtH + (size_t)3 * 512 * 512;

  // 0) transpose+split W into bf16 hi/lo (tiny)
  prep_split_kernel<<<NWsplit, 256, 0, stream>>>(Wq, Wk, Wv, WtH, WtL);

  // 1) q/k/v projections (MFMA bf16x3, B via global_load_lds) + fill rows [0,36864)
  gemm_fill_kernel<<<NGemm + NFillG, 256, 0, stream>>>(
      x_q, x_k, x_v, WtH, WtL, bq, bk, bv, q, kp, vp, fscores);

  // 2) v-mean partials + sampled scores -> M (row-major all-heads) + light fill [36864,45056)
  sampled_m_kernel<<<NVPart + NSampled + NFillS, 64, 0, stream>>>(
      q, kp, idx, Mt, vp, vpart, fscores);

  // 3) register-tournament top-30 + v_mean(from partials) + base row + fill rows [45056,65536)
  topk_vmean_base_kernel<<<36 + NFillT, 256, 0, stream>>>(
      Mt, vpart, Wo, bo, top, vmean, basep, fscores);

  // 4) grouped attention (Gu=2, 480 blocks) + out base fill
  attn_out_kernel<<<NAttnG + NOutF, 256, 0, stream>>>(
      q, kp, vp, vmean, top, Wo, basep, out, fscores);
}